// Round 14
// baseline (171.954 us; speedup 1.0000x reference)
//
#include <hip/hip_runtime.h>
#include <hip/hip_bf16.h>

#define NN 16384          // sequence length
#define NC 16             // layer channels
#define NPOSTOT 131072    // 8 * 16384
#define NLAY 29           // gated layers
#define TOUT 256          // output positions per block

typedef float4 f4;
typedef short bf16x8 __attribute__((ext_vector_type(8)));
typedef float f32x4 __attribute__((ext_vector_type(4)));

// prepack element offsets (in shorts)
#define OFF_WF 0
#define OFF_WG (NLAY * 512)
#define OFF_WR (2 * NLAY * 512)
#define OFF_WA (3 * NLAY * 512)
#define OFF_WO (3 * NLAY * 512 + 2048)
#define PK_TOT (OFF_WO + 16384)

static __device__ __forceinline__ short to_bf16(float f) {
    __hip_bfloat16 h = __float2bfloat16(f);   // RNE
    short s;
    __builtin_memcpy(&s, &h, 2);
    return s;
}
static __device__ __forceinline__ float from_bf16(short s) {
    unsigned int u = ((unsigned int)(unsigned short)s) << 16;
    float f;
    __builtin_memcpy(&f, &u, 4);
    return f;
}

// ---------------- weight prepack into MFMA A-fragments (bf16) -----------------
// Slot-consistency: A and B packed with the same (h=lane>>4, j)->k bijection.
//  conv (K=32):  k = h*8+j ; tap = k>>4, c = k&15           (B from memory)
//  1x1  (K=32):  j<4 -> k = h*4+j (=channel), j>=4 -> zero  (B = conv output)
//  Wa   (K=32):  k = h*8+j, real for k<16 (c=k), else zero  (B from memory)
//  Wo   (K=64):  half hf, k = hf*32 + (j>>2)*16 + h*4 + (j&3)  (B = Wa output)
__global__ __launch_bounds__(256) void prepack_k(
    const float* __restrict__ Wf, const float* __restrict__ Wg,
    const float* __restrict__ Wr, const float* __restrict__ Wa,
    const float* __restrict__ Wo, short* __restrict__ pk)
{
    const int i = blockIdx.x * 256 + threadIdx.x;
    if (i >= PK_TOT) return;
    float val;
    if (i < OFF_WG) {                               // Wf frags
        const int j = i >> 9, r = i & 511, l = r >> 3, j8 = r & 7;
        const int o = l & 15, h = l >> 4;
        const int k = h * 8 + j8, tap = k >> 4, c = k & 15;
        val = Wf[((j * 16 + o) * 16 + c) * 2 + tap];
    } else if (i < OFF_WA) {
        const int i2 = i - OFF_WG;
        if (i2 < NLAY * 512) {                      // Wg frags
            const int j = i2 >> 9, r = i2 & 511, l = r >> 3, j8 = r & 7;
            const int o = l & 15, h = l >> 4;
            const int k = h * 8 + j8, tap = k >> 4, c = k & 15;
            val = Wg[((j * 16 + o) * 16 + c) * 2 + tap];
        } else {                                    // Wr frags (half zero-padded)
            const int i3 = i2 - NLAY * 512;
            const int j = i3 >> 9, r = i3 & 511, l = r >> 3, j8 = r & 7;
            const int o = l & 15, h = l >> 4;
            val = (j8 < 4) ? Wr[j * 256 + o * 16 + h * 4 + j8] : 0.0f;
        }
    } else if (i < OFF_WO) {                        // Wa frags (4 m-tiles)
        const int i2 = i - OFF_WA;
        const int mt = i2 >> 9, r = i2 & 511, l = r >> 3, j8 = r & 7;
        const int og = mt * 16 + (l & 15), h = l >> 4;
        const int k = h * 8 + j8;
        val = (k < 16) ? Wa[og * 16 + k] : 0.0f;
    } else {                                        // Wo frags (16 q-tiles x 2 halves)
        const int i2 = i - OFF_WO;
        const int qt = i2 >> 10, hf = (i2 >> 9) & 1, r = i2 & 511;
        const int l = r >> 3, j8 = r & 7;
        const int q = qt * 16 + (l & 15), h = l >> 4;
        const int kg = hf * 32 + (j8 >> 2) * 16 + h * 4 + (j8 & 3);
        val = Wo[q * 64 + kg];
    }
    pk[i] = to_bf16(val);
}

// ---------------- gated MFMA core: 2 conv MFMA + merged act + 1x1 MFMA -------
static __device__ __forceinline__ f32x4 gated_core2(
    bf16x8 bx, bf16x8 af_, bf16x8 ag_, bf16x8 ar_,
    f32x4 cf, f32x4 cg, f32x4 cr)
{
    const f32x4 fp = __builtin_amdgcn_mfma_f32_16x16x32_bf16(af_, bx, cf, 0, 0, 0);
    const f32x4 gp = __builtin_amdgcn_mfma_f32_16x16x32_bf16(ag_, bx, cg, 0, 0, 0);

    bf16x8 bz;
#pragma unroll
    for (int r = 0; r < 4; ++r) {
        // z = tanh(f)*sigmoid(g) = (e^{2f}-1) / ((e^{2f}+1)(1+e^{-g}))
        const float ef = __expf(2.0f * fminf(fp[r], 43.0f));   // clamp: no inf
        const float eg = __expf(-gp[r]);
        const float den = fmaf(ef, eg, ef) + (eg + 1.0f);
        bz[r] = to_bf16((ef - 1.0f) * __builtin_amdgcn_rcpf(den));
        bz[r + 4] = 0;
    }
    return __builtin_amdgcn_mfma_f32_16x16x32_bf16(ar_, bz, cr, 0, 0, 0);
}

// ---------------- single gated layer, global->global, no LDS / barriers ------
// 512 threads = 8 waves; each wave owns 2 16-pos tiles of the block's 256
// positions. Stream stays L2-resident across the ping-pong (same blockIdx ->
// same XCD across equal-sized dispatches).
struct SegCfg { int d; int jbase; int l0; };

constexpr SegCfg CFGS[NLAY] = {
    {2, 0, 1},   {4, 1, 0},   {8, 2, 0},   {16, 3, 0},  {32, 4, 0},
    {64, 5, 0},  {128, 6, 0}, {256, 7, 0}, {512, 8, 0}, {1, 9, 0},
    {2, 10, 0},  {4, 11, 0},  {8, 12, 0},  {16, 13, 0}, {32, 14, 0},
    {64, 15, 0}, {128, 16, 0},{256, 17, 0},{512, 18, 0},{1, 19, 0},
    {2, 20, 0},  {4, 21, 0},  {8, 22, 0},  {16, 23, 0}, {32, 24, 0},
    {64, 25, 0}, {128, 26, 0},{256, 27, 0},{512, 28, 0},
};

template<int KI>
__global__ __launch_bounds__(512)
void fused_t(const short* __restrict__ src, const float* __restrict__ x,
             const float* __restrict__ W0, const float* __restrict__ b0,
             short* __restrict__ dst, const short* __restrict__ pk,
             const float* __restrict__ bfA, const float* __restrict__ bgA,
             const float* __restrict__ brA)
{
    constexpr SegCfg cfg = CFGS[KI];
    constexpr int d = cfg.d;
    constexpr int j = cfg.jbase;

    const int t = threadIdx.x, lane = t & 63, wv = t >> 6;
    const int h = lane >> 4, i16 = lane & 15;
    const int tap = h >> 1, c0 = (h & 1) * 8;
    const int pbase = blockIdx.x * TOUT;
    const int bb = pbase >> 14, n0 = pbase & (NN - 1);
    const float* xrow = x + (size_t)bb * NN;
    const short* srow = src + (size_t)bb * NN * NC;

    const bf16x8 af = *(const bf16x8*)(pk + OFF_WF + j * 512 + lane * 8);
    const bf16x8 ag = *(const bf16x8*)(pk + OFF_WG + j * 512 + lane * 8);
    const bf16x8 ar = *(const bf16x8*)(pk + OFF_WR + j * 512 + lane * 8);
    const f4 v1 = *(const f4*)(bfA + j * 16 + h * 4);
    const f4 v2 = *(const f4*)(bgA + j * 16 + h * 4);
    const f4 v3 = *(const f4*)(brA + j * 16 + h * 4);
    const f32x4 cf = {v1.x, v1.y, v1.z, v1.w};
    const f32x4 cg = {v2.x, v2.y, v2.z, v2.w};
    const f32x4 cr = {v3.x, v3.y, v3.z, v3.w};

    const int l0r = wv * 32 + i16;      // tile-0 position offset in block
    const int nA = n0 + l0r;
    const int nB = nA + 16;             // tile-1

    auto doTile = [&](int n) {
        const int ns = tap ? n : n - d;
        bf16x8 bx = {0, 0, 0, 0, 0, 0, 0, 0};
        f32x4 rin = {0.0f, 0.0f, 0.0f, 0.0f};
        if (cfg.l0) {
            if (ns >= 0) {              // layer-0 output computed on the fly
                const float xs = xrow[ns] * (1.0f / 32768.0f);
                const float xm = (ns >= 1) ? xrow[ns - 1] * (1.0f / 32768.0f) : 0.0f;
#pragma unroll
                for (int q2 = 0; q2 < 8; ++q2) {
                    const int c = c0 + q2;
                    bx[q2] = to_bf16(xs + fmaf(W0[c * 2], xm,
                                      fmaf(W0[c * 2 + 1], xs, b0[c])));
                }
            }
            {                           // residual input at own position
                const float xs = xrow[n] * (1.0f / 32768.0f);
                const float xm = (n >= 1) ? xrow[n - 1] * (1.0f / 32768.0f) : 0.0f;
                const int c = h * 4;
                rin[0] = xs + fmaf(W0[c * 2 + 0], xm, fmaf(W0[c * 2 + 1], xs, b0[c + 0]));
                rin[1] = xs + fmaf(W0[c * 2 + 2], xm, fmaf(W0[c * 2 + 3], xs, b0[c + 1]));
                rin[2] = xs + fmaf(W0[c * 2 + 4], xm, fmaf(W0[c * 2 + 5], xs, b0[c + 2]));
                rin[3] = xs + fmaf(W0[c * 2 + 6], xm, fmaf(W0[c * 2 + 7], xs, b0[c + 3]));
            }
        } else {
            if (ns >= 0) bx = *(const bf16x8*)(srow + (size_t)ns * NC + c0);
            const short4 ov = *(const short4*)(srow + (size_t)n * NC + h * 4);
            rin[0] = from_bf16(ov.x); rin[1] = from_bf16(ov.y);
            rin[2] = from_bf16(ov.z); rin[3] = from_bf16(ov.w);
        }
        const f32x4 o = gated_core2(bx, af, ag, ar, cf, cg, cr);
        *(short4*)(dst + ((size_t)bb * NN + n) * NC + h * 4) =
            make_short4(to_bf16(rin[0] + o[0]), to_bf16(rin[1] + o[1]),
                        to_bf16(rin[2] + o[2]), to_bf16(rin[3] + o[3]));
    };
    doTile(nA);
    doTile(nB);
}

// ---------------- head: Wo frags in LDS; 512 threads, no spills ---------------
__global__ __launch_bounds__(512, 2) void headm_k(
    const short* __restrict__ fin, const float* __restrict__ x,
    const int* __restrict__ lengths,
    const short* __restrict__ pka, const float* __restrict__ ba,
    const short* __restrict__ pko, const float* __restrict__ bo,
    float* __restrict__ out)
{
    __shared__ short ldsW[16384];            // all Wo fragments, 32 KB

    const int t = threadIdx.x;
    const int lane = t & 63;
    const int wv = t >> 6;
    const int i16 = lane & 15;
    const int h = lane >> 4;
    const int pos = blockIdx.x * 128 + wv * 16 + i16;
    const int b = pos >> 14;
    const int n = pos & (NN - 1);

    // cooperative stage of Wo frags: 512 threads x 4 x 16B coalesced
#pragma unroll
    for (int i = 0; i < 4; ++i)
        ((f4*)ldsW)[t + i * 512] = ((const f4*)pko)[t + i * 512];

    // B fragment for Wa: sk = relu(fin - xs), channels k=h*8+j (real for h<2)
    bf16x8 bs;
    if (h < 2) {
        const float xs = x[pos] * (1.0f / 32768.0f);
        const bf16x8 v = *(const bf16x8*)(fin + (size_t)pos * NC + h * 8);
#pragma unroll
        for (int j = 0; j < 8; ++j)
            bs[j] = to_bf16(fmaxf(from_bf16(v[j]) - xs, 0.0f));
    } else {
#pragma unroll
        for (int j = 0; j < 8; ++j) bs[j] = 0;
    }

    // Wa GEMM: ra = relu(...), 16 values/lane, lane-local for Wo B-frags
    float ra[16];
#pragma unroll
    for (int mt = 0; mt < 4; ++mt) {
        const bf16x8 aa = *(const bf16x8*)(pka + (mt * 64 + lane) * 8);
        const f4 bav = *(const f4*)(ba + mt * 16 + h * 4);
        f32x4 c = {bav.x, bav.y, bav.z, bav.w};
        c = __builtin_amdgcn_mfma_f32_16x16x32_bf16(aa, bs, c, 0, 0, 0);
#pragma unroll
        for (int r = 0; r < 4; ++r) ra[mt * 4 + r] = fmaxf(c[r], 0.0f);
    }
    bf16x8 blo, bhi;
#pragma unroll
    for (int j = 0; j < 8; ++j) { blo[j] = to_bf16(ra[j]); bhi[j] = to_bf16(ra[8 + j]); }

    __syncthreads();   // Wo frags staged

    // Wo GEMM: 16 q-tiles x (2 MFMA, K=64); A-frags from LDS; logits in VGPRs
    float lg[64];
#pragma unroll
    for (int qt = 0; qt < 16; ++qt) {
        const bf16x8 a0 = *(const bf16x8*)(ldsW + ((qt * 2 + 0) * 64 + lane) * 8);
        const bf16x8 a1 = *(const bf16x8*)(ldsW + ((qt * 2 + 1) * 64 + lane) * 8);
        const f4 bov = *(const f4*)(bo + qt * 16 + h * 4);
        f32x4 c = {bov.x, bov.y, bov.z, bov.w};
        c = __builtin_amdgcn_mfma_f32_16x16x32_bf16(a0, blo, c, 0, 0, 0);
        c = __builtin_amdgcn_mfma_f32_16x16x32_bf16(a1, bhi, c, 0, 0, 0);
#pragma unroll
        for (int r = 0; r < 4; ++r) lg[qt * 4 + r] = c[r];
    }

    // LSE across lanes {i, i+16, i+32, i+48}
    float m = lg[0];
#pragma unroll
    for (int j = 1; j < 64; ++j) m = fmaxf(m, lg[j]);
    m = fmaxf(m, __shfl_xor(m, 16, 64));
    m = fmaxf(m, __shfl_xor(m, 32, 64));
    float s = 0.0f;
#pragma unroll
    for (int j = 0; j < 64; ++j) s += __expf(lg[j] - m);
    s += __shfl_xor(s, 16, 64);
    s += __shfl_xor(s, 32, 64);
    const float lse = m + __logf(s);
    const bool valid = n < lengths[b];

    // write: q = qt*16 + h*4 + r at out[b][q][n] (full 64B lines per h-group)
    float* ob = out + (size_t)b * 256 * NN + n;
#pragma unroll
    for (int qt = 0; qt < 16; ++qt)
#pragma unroll
        for (int r = 0; r < 4; ++r)
            ob[(size_t)(qt * 16 + h * 4 + r) * NN] = valid ? (lg[qt * 4 + r] - lse) : 0.0f;
}

extern "C" void kernel_launch(void* const* d_in, const int* in_sizes, int n_in,
                              void* d_out, int out_size, void* d_ws, size_t ws_size,
                              hipStream_t stream)
{
    const float* x       = (const float*)d_in[0];
    const int*   lengths = (const int*)d_in[1];
    const float* W0      = (const float*)d_in[2];
    const float* b0      = (const float*)d_in[3];
    const float* Wf      = (const float*)d_in[4];
    const float* bf      = (const float*)d_in[5];
    const float* Wg      = (const float*)d_in[6];
    const float* bg      = (const float*)d_in[7];
    const float* Wr      = (const float*)d_in[8];
    const float* br      = (const float*)d_in[9];
    const float* Wa      = (const float*)d_in[10];
    const float* ba      = (const float*)d_in[11];
    const float* Wo      = (const float*)d_in[12];
    const float* bo      = (const float*)d_in[13];
    float* out = (float*)d_out;

    short* bufA = (short*)d_ws;                         // (B,N,16) bf16, 4.2 MB
    short* bufB = bufA + (size_t)NPOSTOT * NC;
    short* pk   = bufB + (size_t)NPOSTOT * NC;          // packed weight frags

    prepack_k<<<dim3((PK_TOT + 255) / 256), dim3(256), 0, stream>>>(
        Wf, Wg, Wr, Wa, Wo, pk);

#define FUSED(K, SRC, DST)                                                     \
    fused_t<K><<<dim3(NPOSTOT / TOUT), dim3(512), 0, stream>>>(                \
        SRC, x, W0, b0, DST, pk, bf, bg, br)

    FUSED(0,  bufA, bufA);   // src unused (l0 mode)
    FUSED(1,  bufA, bufB);
    FUSED(2,  bufB, bufA);
    FUSED(3,  bufA, bufB);
    FUSED(4,  bufB, bufA);
    FUSED(5,  bufA, bufB);
    FUSED(6,  bufB, bufA);
    FUSED(7,  bufA, bufB);
    FUSED(8,  bufB, bufA);
    FUSED(9,  bufA, bufB);
    FUSED(10, bufB, bufA);
    FUSED(11, bufA, bufB);
    FUSED(12, bufB, bufA);
    FUSED(13, bufA, bufB);
    FUSED(14, bufB, bufA);
    FUSED(15, bufA, bufB);
    FUSED(16, bufB, bufA);
    FUSED(17, bufA, bufB);
    FUSED(18, bufB, bufA);
    FUSED(19, bufA, bufB);
    FUSED(20, bufB, bufA);
    FUSED(21, bufA, bufB);
    FUSED(22, bufB, bufA);
    FUSED(23, bufA, bufB);
    FUSED(24, bufB, bufA);
    FUSED(25, bufA, bufB);
    FUSED(26, bufB, bufA);
    FUSED(27, bufA, bufB);
    FUSED(28, bufB, bufA);
#undef FUSED

    headm_k<<<dim3(NPOSTOT / 128), dim3(512), 0, stream>>>(
        bufA, x, lengths, pk + OFF_WA, ba, pk + OFF_WO, bo, out);
}